// Round 1
// baseline (10158.571 us; speedup 1.0000x reference)
//
#include <hip/hip_runtime.h>
#include <math.h>

// LlamaAttention forward, fp32 baseline.
//   B=2, S=2048, H=4096, 32 heads x Dh=128.
// Plan: 3x GEMM (QKV) -> RoPE -> flash attention (causal) -> GEMM (Wo).
// Workspace layout (fp32):  K[16M] | V[16M] | attn_out[16M]  = 192 MB.
// Q lives in d_out (final GEMM reads ws only, writes d_out).

#define NB    2
#define SEQ   2048
#define HID   4096
#define NHEAD 32
#define DHEAD 128
#define MROWS (NB * SEQ)   // 4096

// ---------------------------------------------------------------------------
// GEMM:  C[M,N] = A[M,K] @ W[N,K]^T    (nn.Linear, bias-free)
// 64x64 tile, BK=32, 256 threads, 4x4 micro-tile per thread.
// LDS stored k-major with XOR swizzle r^= (k&24): <=2-way conflicts (free).
// ---------------------------------------------------------------------------
constexpr int BMT = 64, BNT = 64, BKT_G = 32;

__global__ __launch_bounds__(256) void gemm_abt(const float* __restrict__ A,
                                                const float* __restrict__ W,
                                                float* __restrict__ C,
                                                int Kdim, int Ndim)
{
    __shared__ float As[BKT_G][BMT];
    __shared__ float Bs[BKT_G][BNT];

    const int bm = blockIdx.x * BMT;
    const int bn = blockIdx.y * BNT;
    const int t  = threadIdx.x;
    const int tx = t & 15;       // 16 -> 4 cols each
    const int ty = t >> 4;       // 16 -> 4 rows each

    // loader mapping: thread covers rows {r0, r0+32}, k-cols [c0, c0+4)
    const int r0 = t >> 3;             // 0..31
    const int c0 = (t & 7) << 2;       // 0,4,...,28
    const int m0 = c0 & 24;            // swizzle mask (constant per thread)

    const float* Ap = A + (size_t)(bm + r0) * Kdim + c0;
    const float* Bp = W + (size_t)(bn + r0) * Kdim + c0;
    const size_t row32 = (size_t)32 * Kdim;

    float acc[4][4] = {};

    for (int k0 = 0; k0 < Kdim; k0 += BKT_G) {
        float4 a0 = *(const float4*)(Ap + k0);
        float4 a1 = *(const float4*)(Ap + k0 + row32);
        float4 b0 = *(const float4*)(Bp + k0);
        float4 b1 = *(const float4*)(Bp + k0 + row32);
        __syncthreads();   // previous iteration's reads done before overwrite
        {
            const int ra = r0 ^ m0;
            const int rb = (r0 + 32) ^ m0;   // == ra + 32 (m0 < 32)
            As[c0+0][ra] = a0.x; As[c0+1][ra] = a0.y; As[c0+2][ra] = a0.z; As[c0+3][ra] = a0.w;
            As[c0+0][rb] = a1.x; As[c0+1][rb] = a1.y; As[c0+2][rb] = a1.z; As[c0+3][rb] = a1.w;
            Bs[c0+0][ra] = b0.x; Bs[c0+1][ra] = b0.y; Bs[c0+2][ra] = b0.z; Bs[c0+3][ra] = b0.w;
            Bs[c0+0][rb] = b1.x; Bs[c0+1][rb] = b1.y; Bs[c0+2][rb] = b1.z; Bs[c0+3][rb] = b1.w;
        }
        __syncthreads();
        #pragma unroll
        for (int kk = 0; kk < BKT_G; ++kk) {
            const int sw = kk & 24;
            float4 a = *(const float4*)&As[kk][(ty * 4) ^ sw];
            float4 b = *(const float4*)&Bs[kk][(tx * 4) ^ sw];
            acc[0][0] += a.x * b.x; acc[0][1] += a.x * b.y; acc[0][2] += a.x * b.z; acc[0][3] += a.x * b.w;
            acc[1][0] += a.y * b.x; acc[1][1] += a.y * b.y; acc[1][2] += a.y * b.z; acc[1][3] += a.y * b.w;
            acc[2][0] += a.z * b.x; acc[2][1] += a.z * b.y; acc[2][2] += a.z * b.z; acc[2][3] += a.z * b.w;
            acc[3][0] += a.w * b.x; acc[3][1] += a.w * b.y; acc[3][2] += a.w * b.z; acc[3][3] += a.w * b.w;
        }
    }

    #pragma unroll
    for (int i = 0; i < 4; ++i) {
        float4 o = make_float4(acc[i][0], acc[i][1], acc[i][2], acc[i][3]);
        *(float4*)(C + (size_t)(bm + ty * 4 + i) * Ndim + bn + tx * 4) = o;
    }
}

// ---------------------------------------------------------------------------
// RoPE (in-place on Q and K). One thread per (b,s,head,j<64) rotation pair.
// ---------------------------------------------------------------------------
__global__ __launch_bounds__(256) void rope_kernel(float* __restrict__ Qb,
                                                   float* __restrict__ Kb,
                                                   const int* __restrict__ pos)
{
    const int idx = blockIdx.x * 256 + threadIdx.x;   // [0, B*S*NH*64) = 2^23
    const int j = idx & 63;
    const int h = (idx >> 6) & (NHEAD - 1);
    const int s = (idx >> 11) & (SEQ - 1);
    const int b = idx >> 22;

    const float tpos = (float)pos[s];
    // inv_freq = 10000^(-j/64) = exp(-j * ln(10000)/64)
    const float invf = expf((float)j * -0.14391156831212787f);
    const float ang  = tpos * invf;
    const float cs = cosf(ang);
    const float sn = sinf(ang);

    const size_t base = (size_t)(b * SEQ + s) * HID + h * DHEAD + j;
    float q0 = Qb[base], q1 = Qb[base + 64];
    Qb[base]      = q0 * cs - q1 * sn;
    Qb[base + 64] = q1 * cs + q0 * sn;
    float k0 = Kb[base], k1 = Kb[base + 64];
    Kb[base]      = k0 * cs - k1 * sn;
    Kb[base + 64] = k1 * cs + k0 * sn;
}

// ---------------------------------------------------------------------------
// Flash attention, causal, fp32. One block per (q-tile of 64 rows, b*head).
// 256 threads as tx in [0,8) (key cols c = tx+8j), ty in [0,32) (2 q-rows).
// Online softmax; per-row state replicated across the 8 tx lanes and kept
// consistent via full butterfly reductions.
// ---------------------------------------------------------------------------
constexpr int BQ = 64, BKV = 32;

__global__ __launch_bounds__(256) void flash_attn(const float* __restrict__ Qb,
                                                  const float* __restrict__ Kb,
                                                  const float* __restrict__ Vb,
                                                  float* __restrict__ Ob)
{
    __shared__ float Qs[BQ][DHEAD + 4];    // [64][132]
    __shared__ float Ks[BKV][DHEAD + 4];   // [32][132]
    __shared__ float Vs[BKV][DHEAD + 4];   // [32][132]
    __shared__ float Ps[BKV][BQ + 4];      // [32][68], c-major for PV

    const int qt = (int)gridDim.x - 1 - (int)blockIdx.x;  // big blocks first
    const int bh = blockIdx.y;
    const int b  = bh >> 5;
    const int h  = bh & 31;
    const int t  = threadIdx.x;
    const int tx = t & 7;
    const int ty = t >> 3;

    // stage Q tile (reused across all k-tiles)
    const float* Qbase = Qb + (size_t)(b * SEQ + qt * BQ) * HID + h * DHEAD;
    #pragma unroll
    for (int i = 0; i < 8; ++i) {
        int idx = t + 256 * i;             // 2048 float4s
        int r = idx >> 5, c4 = (idx & 31) << 2;
        *(float4*)&Qs[r][c4] = *(const float4*)(Qbase + (size_t)r * HID + c4);
    }

    float4 accv[2][4];
    #pragma unroll
    for (int i = 0; i < 2; ++i)
        #pragma unroll
        for (int q = 0; q < 4; ++q) accv[i][q] = make_float4(0.f, 0.f, 0.f, 0.f);
    float Mrow[2] = {-3.0e38f, -3.0e38f};
    float Lrow[2] = {0.f, 0.f};
    const float scale = 0.08838834764831845f;   // 128^-0.5

    const int ktiles = 2 * qt + 2;              // causal: keys <= qt*64+63
    for (int kt = 0; kt < ktiles; ++kt) {
        __syncthreads();                        // prev PV done before restage
        const float* Kt = Kb + (size_t)(b * SEQ + kt * BKV) * HID + h * DHEAD;
        const float* Vt = Vb + (size_t)(b * SEQ + kt * BKV) * HID + h * DHEAD;
        #pragma unroll
        for (int i = 0; i < 4; ++i) {
            int idx = t + 256 * i;             // 1024 float4s each
            int r = idx >> 5, c4 = (idx & 31) << 2;
            *(float4*)&Ks[r][c4] = *(const float4*)(Kt + (size_t)r * HID + c4);
            *(float4*)&Vs[r][c4] = *(const float4*)(Vt + (size_t)r * HID + c4);
        }
        __syncthreads();

        // ---- scores: 2 rows x 4 cols per thread ----
        float sc[2][4] = {};
        #pragma unroll 4
        for (int dk = 0; dk < DHEAD; dk += 4) {
            float4 qa = *(const float4*)&Qs[ty * 2 + 0][dk];
            float4 qb = *(const float4*)&Qs[ty * 2 + 1][dk];
            #pragma unroll
            for (int j = 0; j < 4; ++j) {
                float4 kv = *(const float4*)&Ks[tx + 8 * j][dk];
                sc[0][j] += qa.x * kv.x; sc[0][j] += qa.y * kv.y;
                sc[0][j] += qa.z * kv.z; sc[0][j] += qa.w * kv.w;
                sc[1][j] += qb.x * kv.x; sc[1][j] += qb.y * kv.y;
                sc[1][j] += qb.z * kv.z; sc[1][j] += qb.w * kv.w;
            }
        }

        // ---- scale + causal mask + online softmax ----
        const int rowg0 = qt * BQ + ty * 2;
        const int colg0 = kt * BKV + tx;
        float mloc[2];
        #pragma unroll
        for (int i = 0; i < 2; ++i) {
            #pragma unroll
            for (int j = 0; j < 4; ++j) {
                float v = sc[i][j] * scale;
                v = ((colg0 + 8 * j) > (rowg0 + i)) ? -1.0e30f : v;
                sc[i][j] = v;
            }
            mloc[i] = fmaxf(fmaxf(sc[i][0], sc[i][1]), fmaxf(sc[i][2], sc[i][3]));
        }
        #pragma unroll
        for (int off = 1; off < 8; off <<= 1) {
            mloc[0] = fmaxf(mloc[0], __shfl_xor(mloc[0], off));
            mloc[1] = fmaxf(mloc[1], __shfl_xor(mloc[1], off));
        }
        float f[2], ssum[2];
        #pragma unroll
        for (int i = 0; i < 2; ++i) {
            float Mnew = fmaxf(Mrow[i], mloc[i]);
            f[i] = expf(Mrow[i] - Mnew);
            Mrow[i] = Mnew;
            float s0 = 0.f;
            #pragma unroll
            for (int j = 0; j < 4; ++j) {
                float p = expf(sc[i][j] - Mnew);
                sc[i][j] = p;
                s0 += p;
            }
            ssum[i] = s0;
        }
        #pragma unroll
        for (int off = 1; off < 8; off <<= 1) {
            ssum[0] += __shfl_xor(ssum[0], off);
            ssum[1] += __shfl_xor(ssum[1], off);
        }
        #pragma unroll
        for (int i = 0; i < 2; ++i) {
            Lrow[i] = Lrow[i] * f[i] + ssum[i];
            #pragma unroll
            for (int q = 0; q < 4; ++q) {
                accv[i][q].x *= f[i]; accv[i][q].y *= f[i];
                accv[i][q].z *= f[i]; accv[i][q].w *= f[i];
            }
        }
        #pragma unroll
        for (int j = 0; j < 4; ++j) {
            Ps[tx + 8 * j][ty * 2 + 0] = sc[0][j];
            Ps[tx + 8 * j][ty * 2 + 1] = sc[1][j];
        }
        __syncthreads();

        // ---- PV: O += P @ V ; thread's d-cols are tx*4 + 32q (conflict-free)
        #pragma unroll 4
        for (int c = 0; c < BKV; ++c) {
            float2 p = *(const float2*)&Ps[c][ty * 2];
            #pragma unroll
            for (int q = 0; q < 4; ++q) {
                float4 v = *(const float4*)&Vs[c][tx * 4 + 32 * q];
                accv[0][q].x += p.x * v.x; accv[0][q].y += p.x * v.y;
                accv[0][q].z += p.x * v.z; accv[0][q].w += p.x * v.w;
                accv[1][q].x += p.y * v.x; accv[1][q].y += p.y * v.y;
                accv[1][q].z += p.y * v.z; accv[1][q].w += p.y * v.w;
            }
        }
    }

    const float inv0 = 1.f / Lrow[0];
    const float inv1 = 1.f / Lrow[1];
    float* Obase = Ob + (size_t)(b * SEQ + qt * BQ + ty * 2) * HID + h * DHEAD;
    #pragma unroll
    for (int q = 0; q < 4; ++q) {
        float4 o0 = make_float4(accv[0][q].x * inv0, accv[0][q].y * inv0,
                                accv[0][q].z * inv0, accv[0][q].w * inv0);
        float4 o1 = make_float4(accv[1][q].x * inv1, accv[1][q].y * inv1,
                                accv[1][q].z * inv1, accv[1][q].w * inv1);
        *(float4*)(Obase + tx * 4 + 32 * q)       = o0;
        *(float4*)(Obase + HID + tx * 4 + 32 * q) = o1;
    }
}

// ---------------------------------------------------------------------------
extern "C" void kernel_launch(void* const* d_in, const int* in_sizes, int n_in,
                              void* d_out, int out_size, void* d_ws, size_t ws_size,
                              hipStream_t stream)
{
    const float* hs  = (const float*)d_in[0];   // [2,2048,4096]
    const float* Wq  = (const float*)d_in[1];   // [4096,4096]
    const float* Wk  = (const float*)d_in[2];
    const float* Wv  = (const float*)d_in[3];
    const float* Wo  = (const float*)d_in[4];
    // d_in[5] = attn_mask (causal; reproduced analytically, not read)
    const int*   pos = (const int*)d_in[6];     // [1,2048]

    float* Qb = (float*)d_out;                         // Q scratch lives in d_out
    float* Kb = (float*)d_ws;
    float* Vb = Kb + (size_t)MROWS * HID;
    float* Ab = Vb + (size_t)MROWS * HID;              // attention output

    dim3 gg(MROWS / BMT, HID / BNT);                   // (64, 64)
    gemm_abt<<<gg, 256, 0, stream>>>(hs, Wq, Qb, HID, HID);
    gemm_abt<<<gg, 256, 0, stream>>>(hs, Wk, Kb, HID, HID);
    gemm_abt<<<gg, 256, 0, stream>>>(hs, Wv, Vb, HID, HID);

    rope_kernel<<<(NB * SEQ * NHEAD * 64) / 256, 256, 0, stream>>>(Qb, Kb, pos);

    dim3 fg(SEQ / BQ, NB * NHEAD);                     // (32, 64)
    flash_attn<<<fg, 256, 0, stream>>>(Qb, Kb, Vb, Ab);

    gemm_abt<<<gg, 256, 0, stream>>>(Ab, Wo, (float*)d_out, HID, HID);
}

// Round 2
// 3248.690 us; speedup vs baseline: 3.1270x; 3.1270x over previous
//
#include <hip/hip_runtime.h>
#include <math.h>

// LlamaAttention forward. B=2, S=2048, H=4096, 32 heads x Dh=128.
// Round 1: bf16 MFMA GEMMs (m97 structure, ~874 TF verified at 4096^3).
// Numerics: Q,K kept fp32 through RoPE+scores; X/W/V/attn-out bf16.
// ws: Kf32[64MB] | Vbf[32] | Xbf[32] | Wbf[32, reused] | Abf[32] = 192MB.

typedef unsigned short u16;
typedef __attribute__((ext_vector_type(8))) short bf16x8;
typedef __attribute__((ext_vector_type(4))) float f32x4;

#define NB    2
#define SEQ   2048
#define HID   4096
#define NHEAD 32
#define DHEAD 128
#define MROWS (NB * SEQ)   // 4096

__device__ __forceinline__ u16 f2bf(float x) {
    union { float f; unsigned u; } v; v.f = x;
    unsigned r = (v.u + 0x7FFFu + ((v.u >> 16) & 1u)) >> 16;   // RNE
    return (u16)r;
}
__device__ __forceinline__ float bf2f(u16 u) {
    union { unsigned u; float f; } v; v.u = ((unsigned)u) << 16; return v.f;
}

#define GLD16(g, l) __builtin_amdgcn_global_load_lds(                     \
    (const __attribute__((address_space(1))) void*)(g),                   \
    (__attribute__((address_space(3))) void*)(l), 16, 0, 0)

// ---------------------------------------------------------------------------
// f32 -> bf16 cast, vectorized (float4 -> ushort4 per thread)
// ---------------------------------------------------------------------------
__global__ __launch_bounds__(256) void f32_to_bf16_k(const float* __restrict__ in,
                                                     u16* __restrict__ out, int n4)
{
    int i = blockIdx.x * 256 + threadIdx.x;
    if (i >= n4) return;
    float4 v = ((const float4*)in)[i];
    ushort4 o;
    o.x = f2bf(v.x); o.y = f2bf(v.y); o.z = f2bf(v.z); o.w = f2bf(v.w);
    ((ushort4*)out)[i] = o;
}

// ---------------------------------------------------------------------------
// bf16 GEMM:  C[M,N] = A[M,K] @ W[N,K]^T   (both row-major, K contiguous)
// m97 structure: 128x128 tile, BK=32, 256 thr (4 waves, 2x2), 4x4 frags of
// mfma_f32_16x16x32_bf16 per wave. global_load_lds width=16 with the swizzle
// applied on the GLOBAL source (LDS dest stays linear); ds_read_b128 reads
// use slot = kc ^ ((row>>1)&3)  -> 2-way (free) bank aliasing.
// OBF=0: f32 output, OBF=1: bf16 output.
// ---------------------------------------------------------------------------
constexpr int BMg = 128, BNg = 128, BKg = 32;

template <int OBF>
__global__ __launch_bounds__(256) void gemm_bt(const u16* __restrict__ A,
                                               const u16* __restrict__ W,
                                               void* __restrict__ Cv,
                                               int Kdim, int Ndim)
{
    __shared__ u16 As[BMg * BKg];   // 8 KB, [row][slot*8..] with swizzled content
    __shared__ u16 Bs[BNg * BKg];   // 8 KB

    const int bm = blockIdx.x * BMg;
    const int bn = blockIdx.y * BNg;
    const int t    = threadIdx.x;
    const int lane = t & 63;
    const int w    = t >> 6;        // wave 0..3
    const int wr   = w >> 1, wc = w & 1;

    // -- staging map: wave w stages LDS-linear issues {2w, 2w+1} of 1KB each.
    //    LDS(row, slot) must hold global k-chunk  slot ^ ((row>>1)&3).
    const u16* agp[2]; const u16* bgp[2]; u16* alp[2]; u16* blp[2];
    #pragma unroll
    for (int j = 0; j < 2; ++j) {
        int row = w * 32 + j * 16 + (lane >> 2);
        int kc  = (lane & 3) ^ ((row >> 1) & 3);
        agp[j] = A + (size_t)(bm + row) * Kdim + kc * 8;
        bgp[j] = W + (size_t)(bn + row) * Kdim + kc * 8;
        alp[j] = &As[(2 * w + j) * 512];
        blp[j] = &Bs[(2 * w + j) * 512];
    }

    // -- fragment read offsets (ushort units)
    const int l16 = lane & 15;
    const int kq  = lane >> 4;      // k-chunk 0..3 (8 bf16 each)
    int aoff[4], boff[4];
    #pragma unroll
    for (int m = 0; m < 4; ++m) {
        int ra = wr * 64 + m * 16 + l16;
        aoff[m] = ra * 32 + (kq ^ ((ra >> 1) & 3)) * 8;
        int rb = wc * 64 + m * 16 + l16;
        boff[m] = rb * 32 + (kq ^ ((rb >> 1) & 3)) * 8;
    }

    f32x4 acc[4][4];
    #pragma unroll
    for (int m = 0; m < 4; ++m)
        #pragma unroll
        for (int n = 0; n < 4; ++n)
            acc[m][n] = (f32x4){0.f, 0.f, 0.f, 0.f};

    for (int k0 = 0; k0 < Kdim; k0 += BKg) {
        __syncthreads();                    // prev tile's readers done
        GLD16(agp[0] + k0, alp[0]);
        GLD16(agp[1] + k0, alp[1]);
        GLD16(bgp[0] + k0, blp[0]);
        GLD16(bgp[1] + k0, blp[1]);
        __syncthreads();                    // drains vmcnt -> tile ready

        bf16x8 af[4], bf[4];
        #pragma unroll
        for (int m = 0; m < 4; ++m) af[m] = *(const bf16x8*)&As[aoff[m]];
        #pragma unroll
        for (int n = 0; n < 4; ++n) bf[n] = *(const bf16x8*)&Bs[boff[n]];
        #pragma unroll
        for (int m = 0; m < 4; ++m)
            #pragma unroll
            for (int n = 0; n < 4; ++n)
                acc[m][n] = __builtin_amdgcn_mfma_f32_16x16x32_bf16(af[m], bf[n], acc[m][n], 0, 0, 0);
    }

    // -- epilogue: D col = lane&15, rows = (lane>>4)*4 + j  (verified m89/m91)
    const int r0 = (lane >> 4) * 4;
    #pragma unroll
    for (int m = 0; m < 4; ++m) {
        #pragma unroll
        for (int n = 0; n < 4; ++n) {
            const size_t base = (size_t)(bm + wr * 64 + m * 16 + r0) * Ndim
                              + bn + wc * 64 + n * 16 + l16;
            if (OBF) {
                u16* C = (u16*)Cv;
                #pragma unroll
                for (int j = 0; j < 4; ++j) C[base + (size_t)j * Ndim] = f2bf(acc[m][n][j]);
            } else {
                float* C = (float*)Cv;
                #pragma unroll
                for (int j = 0; j < 4; ++j) C[base + (size_t)j * Ndim] = acc[m][n][j];
            }
        }
    }
}

// ---------------------------------------------------------------------------
// RoPE (in-place, fp32 Q and K). One thread per (b,s,head,j<64) pair.
// ---------------------------------------------------------------------------
__global__ __launch_bounds__(256) void rope_kernel(float* __restrict__ Qb,
                                                   float* __restrict__ Kb,
                                                   const int* __restrict__ pos)
{
    const int idx = blockIdx.x * 256 + threadIdx.x;
    const int j = idx & 63;
    const int h = (idx >> 6) & (NHEAD - 1);
    const int s = (idx >> 11) & (SEQ - 1);
    const int b = idx >> 22;

    const float tpos = (float)pos[s];
    const float invf = expf((float)j * -0.14391156831212787f);  // 10000^(-j/64)
    const float ang  = tpos * invf;
    const float cs = cosf(ang);
    const float sn = sinf(ang);

    const size_t base = (size_t)(b * SEQ + s) * HID + h * DHEAD + j;
    float q0 = Qb[base], q1 = Qb[base + 64];
    Qb[base]      = q0 * cs - q1 * sn;
    Qb[base + 64] = q1 * cs + q0 * sn;
    float k0 = Kb[base], k1 = Kb[base + 64];
    Kb[base]      = k0 * cs - k1 * sn;
    Kb[base + 64] = k1 * cs + k0 * sn;
}

// ---------------------------------------------------------------------------
// Flash attention, causal. Q,K fp32; V bf16 in; out bf16.
// One block per (64-row q-tile, b*head); 256 thr: tx in [0,8) key cols,
// ty in [0,32) -> 2 q-rows. fp32 VALU core (unchanged from round 0).
// ---------------------------------------------------------------------------
constexpr int BQ = 64, BKV = 32;

__global__ __launch_bounds__(256) void flash_attn(const float* __restrict__ Qb,
                                                  const float* __restrict__ Kb,
                                                  const u16* __restrict__ Vb,
                                                  u16* __restrict__ Ob)
{
    __shared__ float Qs[BQ][DHEAD + 4];
    __shared__ float Ks[BKV][DHEAD + 4];
    __shared__ float Vs[BKV][DHEAD + 4];
    __shared__ float Ps[BKV][BQ + 4];

    const int qt = (int)gridDim.x - 1 - (int)blockIdx.x;   // big tiles first
    const int bh = blockIdx.y;
    const int b  = bh >> 5;
    const int h  = bh & 31;
    const int t  = threadIdx.x;
    const int tx = t & 7;
    const int ty = t >> 3;

    const float* Qbase = Qb + (size_t)(b * SEQ + qt * BQ) * HID + h * DHEAD;
    #pragma unroll
    for (int i = 0; i < 8; ++i) {
        int idx = t + 256 * i;
        int r = idx >> 5, c4 = (idx & 31) << 2;
        *(float4*)&Qs[r][c4] = *(const float4*)(Qbase + (size_t)r * HID + c4);
    }

    float4 accv[2][4];
    #pragma unroll
    for (int i = 0; i < 2; ++i)
        #pragma unroll
        for (int q = 0; q < 4; ++q) accv[i][q] = make_float4(0.f, 0.f, 0.f, 0.f);
    float Mrow[2] = {-3.0e38f, -3.0e38f};
    float Lrow[2] = {0.f, 0.f};
    const float scale = 0.08838834764831845f;

    const int ktiles = 2 * qt + 2;
    for (int kt = 0; kt < ktiles; ++kt) {
        __syncthreads();
        const float* Kt = Kb + (size_t)(b * SEQ + kt * BKV) * HID + h * DHEAD;
        const u16*   Vt = Vb + (size_t)(b * SEQ + kt * BKV) * HID + h * DHEAD;
        #pragma unroll
        for (int i = 0; i < 4; ++i) {
            int idx = t + 256 * i;
            int r = idx >> 5, c4 = (idx & 31) << 2;
            *(float4*)&Ks[r][c4] = *(const float4*)(Kt + (size_t)r * HID + c4);
            ushort4 rv = *(const ushort4*)(Vt + (size_t)r * HID + c4);
            float4 vf = make_float4(bf2f(rv.x), bf2f(rv.y), bf2f(rv.z), bf2f(rv.w));
            *(float4*)&Vs[r][c4] = vf;
        }
        __syncthreads();

        float sc[2][4] = {};
        #pragma unroll 4
        for (int dk = 0; dk < DHEAD; dk += 4) {
            float4 qa = *(const float4*)&Qs[ty * 2 + 0][dk];
            float4 qb = *(const float4*)&Qs[ty * 2 + 1][dk];
            #pragma unroll
            for (int j = 0; j < 4; ++j) {
                float4 kv = *(const float4*)&Ks[tx + 8 * j][dk];
                sc[0][j] += qa.x * kv.x; sc[0][j] += qa.y * kv.y;
                sc[0][j] += qa.z * kv.z; sc[0][j] += qa.w * kv.w;
                sc[1][j] += qb.x * kv.x; sc[1][j] += qb.y * kv.y;
                sc[1][j] += qb.z * kv.z; sc[1][j] += qb.w * kv.w;
            }
        }

        const int rowg0 = qt * BQ + ty * 2;
        const int colg0 = kt * BKV + tx;
        float mloc[2];
        #pragma unroll
        for (int i = 0; i < 2; ++i) {
            #pragma unroll
            for (int j = 0; j < 4; ++j) {
                float v = sc[i][j] * scale;
                v = ((colg0 + 8 * j) > (rowg0 + i)) ? -1.0e30f : v;
                sc[i][j] = v;
            }
            mloc[i] = fmaxf(fmaxf(sc[i][0], sc[i][1]), fmaxf(sc[i][2], sc[i][3]));
        }
        #pragma unroll
        for (int off = 1; off < 8; off <<= 1) {
            mloc[0] = fmaxf(mloc[0], __shfl_xor(mloc[0], off));
            mloc[1] = fmaxf(mloc[1], __shfl_xor(mloc[1], off));
        }
        float f[2], ssum[2];
        #pragma unroll
        for (int i = 0; i < 2; ++i) {
            float Mnew = fmaxf(Mrow[i], mloc[i]);
            f[i] = expf(Mrow[i] - Mnew);
            Mrow[i] = Mnew;
            float s0 = 0.f;
            #pragma unroll
            for (int j = 0; j < 4; ++j) {
                float p = expf(sc[i][j] - Mnew);
                sc[i][j] = p;
                s0 += p;
            }
            ssum[i] = s0;
        }
        #pragma unroll
        for (int off = 1; off < 8; off <<= 1) {
            ssum[0] += __shfl_xor(ssum[0], off);
            ssum[1] += __shfl_xor(ssum[1], off);
        }
        #pragma unroll
        for (int i = 0; i < 2; ++i) {
            Lrow[i] = Lrow[i] * f[i] + ssum[i];
            #pragma unroll
            for (int q = 0; q < 4; ++q) {
                accv[i][q].x *= f[i]; accv[i][q].y *= f[i];
                accv[i][q].z *= f[i]; accv[i][q].w *= f[i];
            }
        }
        #pragma unroll
        for (int j = 0; j < 4; ++j) {
            Ps[tx + 8 * j][ty * 2 + 0] = sc[0][j];
            Ps[tx + 8 * j][ty * 2 + 1] = sc[1][j];
        }
        __syncthreads();

        #pragma unroll 4
        for (int c = 0; c < BKV; ++c) {
            float2 p = *(const float2*)&Ps[c][ty * 2];
            #pragma unroll
            for (int q = 0; q < 4; ++q) {
                float4 v = *(const float4*)&Vs[c][tx * 4 + 32 * q];
                accv[0][q].x += p.x * v.x; accv[0][q].y += p.x * v.y;
                accv[0][q].z += p.x * v.z; accv[0][q].w += p.x * v.w;
                accv[1][q].x += p.y * v.x; accv[1][q].y += p.y * v.y;
                accv[1][q].z += p.y * v.z; accv[1][q].w += p.y * v.w;
            }
        }
    }

    const float inv0 = 1.f / Lrow[0];
    const float inv1 = 1.f / Lrow[1];
    u16* Obase = Ob + (size_t)(b * SEQ + qt * BQ + ty * 2) * HID + h * DHEAD;
    #pragma unroll
    for (int q = 0; q < 4; ++q) {
        ushort4 o0, o1;
        o0.x = f2bf(accv[0][q].x * inv0); o0.y = f2bf(accv[0][q].y * inv0);
        o0.z = f2bf(accv[0][q].z * inv0); o0.w = f2bf(accv[0][q].w * inv0);
        o1.x = f2bf(accv[1][q].x * inv1); o1.y = f2bf(accv[1][q].y * inv1);
        o1.z = f2bf(accv[1][q].z * inv1); o1.w = f2bf(accv[1][q].w * inv1);
        *(ushort4*)(Obase + tx * 4 + 32 * q)       = o0;
        *(ushort4*)(Obase + HID + tx * 4 + 32 * q) = o1;
    }
}

// ---------------------------------------------------------------------------
extern "C" void kernel_launch(void* const* d_in, const int* in_sizes, int n_in,
                              void* d_out, int out_size, void* d_ws, size_t ws_size,
                              hipStream_t stream)
{
    const float* hs  = (const float*)d_in[0];
    const float* Wq  = (const float*)d_in[1];
    const float* Wk  = (const float*)d_in[2];
    const float* Wv  = (const float*)d_in[3];
    const float* Wo  = (const float*)d_in[4];
    const int*   pos = (const int*)d_in[6];

    float* Qf = (float*)d_out;                          // Q fp32 lives in d_out
    uint8_t* ws = (uint8_t*)d_ws;
    float* Kf  = (float*)ws;                            // 64 MB fp32
    u16*   Vbf = (u16*)(ws + ((size_t)64 << 20));       // 32 MB bf16
    u16*   Xbf = (u16*)(ws + ((size_t)96 << 20));       // 32 MB bf16
    u16*   Wbf = (u16*)(ws + ((size_t)128 << 20));      // 32 MB bf16 (reused)
    u16*   Abf = (u16*)(ws + ((size_t)160 << 20));      // 32 MB bf16

    const int n4 = MROWS * HID / 4;                     // 4M float4s
    const int cvb = n4 / 256;                           // 16384 blocks
    dim3 gg(MROWS / BMg, HID / BNg);                    // (32, 32)

    f32_to_bf16_k<<<cvb, 256, 0, stream>>>(hs, Xbf, n4);

    f32_to_bf16_k<<<cvb, 256, 0, stream>>>(Wq, Wbf, n4);
    gemm_bt<0><<<gg, 256, 0, stream>>>(Xbf, Wbf, Qf, HID, HID);

    f32_to_bf16_k<<<cvb, 256, 0, stream>>>(Wk, Wbf, n4);
    gemm_bt<0><<<gg, 256, 0, stream>>>(Xbf, Wbf, Kf, HID, HID);

    f32_to_bf16_k<<<cvb, 256, 0, stream>>>(Wv, Wbf, n4);
    gemm_bt<1><<<gg, 256, 0, stream>>>(Xbf, Wbf, Vbf, HID, HID);

    rope_kernel<<<(NB * SEQ * NHEAD * 64) / 256, 256, 0, stream>>>(Qf, Kf, pos);

    dim3 fg(SEQ / BQ, NB * NHEAD);                      // (32, 64)
    flash_attn<<<fg, 256, 0, stream>>>(Qf, Kf, Vbf, Abf);

    f32_to_bf16_k<<<cvb, 256, 0, stream>>>(Wo, Wbf, n4);
    gemm_bt<0><<<gg, 256, 0, stream>>>(Abf, Wbf, (float*)d_out, HID, HID);
}